// Round 15
// baseline (537.042 us; speedup 1.0000x reference)
//
#include <hip/hip_runtime.h>
#include <hip/hip_bf16.h>
#include <stdint.h>

#define SEQLEN 512
#define NBATCH 64
#define KDIM   512
#define HDIM   1024
#define MTOT   (SEQLEN * NBATCH)   // 32768
#define NTOT   (3 * HDIM)          // 3072
#define STRIDE (NBATCH * HDIM)     // 65536

typedef __attribute__((ext_vector_type(2))) float f32x2;
typedef __attribute__((ext_vector_type(4))) float f32x4;
typedef _Float16 f16x8 __attribute__((ext_vector_type(8)));

// ---------- merged conversion: x and U -> (hi, lo) fp16 planes -----------
// 3-pass MFMA (AhBh+AhBl+AlBh) ~= fp32 GEMM (r5: 2-pass fails at 0.51).
#define XTHREADS (MTOT * KDIM / 8)   // 2,097,152
#define UTHREADS (NTOT * KDIM / 8)   //   196,608
__global__ __launch_bounds__(256) void cvt_all(const float* __restrict__ x,
                                               const float* __restrict__ Uc,
                                               const float* __restrict__ Ua,
                                               const float* __restrict__ Uh,
                                               _Float16* __restrict__ xh,
                                               _Float16* __restrict__ xl,
                                               _Float16* __restrict__ uh,
                                               _Float16* __restrict__ ul) {
    int i = blockIdx.x * 256 + threadIdx.x;
    const float* src;
    _Float16 *dh, *dl;
    size_t off;
    if (i < XTHREADS) {
        src = x + (size_t)i * 8;
        off = (size_t)i * 8;
        dh = xh; dl = xl;
    } else {
        int u = i - XTHREADS;
        int n = u >> 6;
        int kb = (u & 63) * 8;
        src = ((n < HDIM) ? (Uc + (size_t)n * KDIM)
             : (n < 2 * HDIM) ? (Ua + (size_t)(n - HDIM) * KDIM)
             : (Uh + (size_t)(n - 2 * HDIM) * KDIM)) + kb;
        off = (size_t)n * KDIM + kb;
        dh = uh; dl = ul;
    }
    const float4* s = (const float4*)src;
    float4 a = s[0], b = s[1];
    float v[8] = {a.x, a.y, a.z, a.w, b.x, b.y, b.z, b.w};
    f16x8 hi, lo;
#pragma unroll
    for (int j = 0; j < 8; ++j) {
        _Float16 h = (_Float16)v[j];
        hi[j] = h;
        lo[j] = (_Float16)(v[j] - (float)h);
    }
    *(f16x8*)(dh + off) = hi;
    *(f16x8*)(dl + off) = lo;
}

// --------- GEMM: proj[M][3072] = (Xh+Xl)·(Uh+Ul)^T, 3-pass split ---------
// Round-15 = round-6 kernel EXACTLY (best of 7 schedules: 281us, MfmaUtil 52,
// 0 conflicts) with one change: pc/pa epilogue writes the (s-pair, idx)
// interleaved layout {pc(2p),pc(2p+1),pa(2p),pa(2p+1)} so recur can load
// float4 per 2 steps (in-flight bytes 12.3->24.6 KB/SIMD, vmcnt-slot bound).
// s = m>>6 (M dim is s*64+b): the s-pair of acc[ai] is acc[ai+4], same b.
#define BM 256
#define BN 256
#define BK 32
#define NT_N (NTOT / BN)            // 12
#define GRID ((MTOT / BM) * NT_N)   // 1536
#define KT_N (KDIM / BK)            // 16

__device__ __forceinline__ void gload16(const _Float16* g, _Float16* l) {
    __builtin_amdgcn_global_load_lds((const __attribute__((address_space(1))) void*)g,
                                     (__attribute__((address_space(3))) void*)l,
                                     16, 0, 0);
}

__device__ __forceinline__ f32x4 mfma16(f16x8 a, f16x8 b, f32x4 c) {
    return __builtin_amdgcn_mfma_f32_16x16x32_f16(a, b, c, 0, 0, 0);
}

__global__ __launch_bounds__(512, 2) void gemm_f16x2(const _Float16* __restrict__ Ah,
                                                     const _Float16* __restrict__ Al,
                                                     const _Float16* __restrict__ Bh,
                                                     const _Float16* __restrict__ Bl,
                                                     float* __restrict__ pcpa,
                                                     float* __restrict__ out) {
    // [buf][plane][256 rows * 32 f16]; plane 0=Ah 1=Al 2=Bh 3=Bl. 128 KB.
    __shared__ _Float16 lds[2][4][BM * BK];

    int bid  = blockIdx.x;          // default order, A-panel-major
    int bm   = bid / NT_N;
    int bn   = bid % NT_N;
    int tid  = threadIdx.x;
    int lane = tid & 63;
    int wave = tid >> 6;
    int wr   = wave >> 2;           // 0..1 (M half, 128 rows)
    int wc   = wave & 3;            // 0..3 (N quarter, 64 cols)

    // staging (T2 source-side chunk permute; measured conflict-free r3-r14)
    size_t row_off = (size_t)(tid >> 2) * KDIM
                   + (size_t)(((tid & 3) ^ ((tid >> 3) & 3)) * 8);
    const _Float16* gAh = Ah + (size_t)bm * BM * KDIM + row_off;
    const _Float16* gAl = Al + (size_t)bm * BM * KDIM + row_off;
    const _Float16* gBh = Bh + (size_t)bn * BN * KDIM + row_off;
    const _Float16* gBl = Bl + (size_t)bn * BN * KDIM + row_off;
    const size_t P128 = (size_t)128 * KDIM;   // +128 rows in global
    int t8 = tid * 8;

#define SPAIR(buf, plane, gp, kt) do { int _g = (kt) * BK;                     \
    gload16((gp) + _g,        &lds[buf][plane][t8]);                           \
    gload16((gp) + P128 + _g, &lds[buf][plane][t8 + 4096]); } while (0)

    f32x4 acc[8][4];
#pragma unroll
    for (int i = 0; i < 8; ++i)
#pragma unroll
        for (int j = 0; j < 4; ++j)
            acc[i][j] = (f32x4){0.f, 0.f, 0.f, 0.f};

    int ro = lane & 15;
    int ko = ((lane >> 4) ^ ((lane >> 1) & 3)) * 8;   // read-side swizzle

    f16x8 a_[4][2], b_[4][2];

#define READ_A(mh) _Pragma("unroll")                                           \
    for (int i = 0; i < 4; ++i) {                                              \
        int row = wr * 128 + ((mh) * 4 + i) * 16 + ro;                         \
        a_[i][0] = *(const f16x8*)(&lds[cur][0][row * BK + ko]);               \
        a_[i][1] = *(const f16x8*)(&lds[cur][1][row * BK + ko]);               \
    }
#define READ_B() _Pragma("unroll")                                             \
    for (int j = 0; j < 4; ++j) {                                              \
        int row = wc * 64 + j * 16 + ro;                                       \
        b_[j][0] = *(const f16x8*)(&lds[cur][2][row * BK + ko]);               \
        b_[j][1] = *(const f16x8*)(&lds[cur][3][row * BK + ko]);               \
    }
#define MFMA_HALF(mh) _Pragma("unroll")                                        \
    for (int i = 0; i < 4; ++i) _Pragma("unroll")                              \
        for (int j = 0; j < 4; ++j) {                                          \
            f32x4 c = acc[(mh) * 4 + i][j];                                    \
            c = mfma16(a_[i][0], b_[j][1], c);   /* Ah·Bl */                   \
            c = mfma16(a_[i][1], b_[j][0], c);   /* Al·Bh */                   \
            c = mfma16(a_[i][0], b_[j][0], c);   /* Ah·Bh */                   \
            acc[(mh) * 4 + i][j] = c;                                          \
        }

    // prologue: tile 0 -> buf 0 (8 loads)
    SPAIR(0, 0, gAh, 0); SPAIR(0, 1, gAl, 0);
    SPAIR(0, 2, gBh, 0); SPAIR(0, 3, gBl, 0);

    for (int kt = 0; kt < KT_N; ++kt) {
        int cur = kt & 1, nxt = 1 - cur;
        bool pre = (kt < KT_N - 1);
        __builtin_amdgcn_sched_barrier(0);
        asm volatile("s_waitcnt vmcnt(0)" ::: "memory");
        __builtin_amdgcn_s_barrier();
        __builtin_amdgcn_sched_barrier(0);

        READ_B();
        READ_A(0);
        if (pre) { SPAIR(nxt, 0, gAh, kt + 1); SPAIR(nxt, 1, gAl, kt + 1); }
        __builtin_amdgcn_s_setprio(1);
        MFMA_HALF(0);
        __builtin_amdgcn_s_setprio(0);
        READ_A(1);
        if (pre) { SPAIR(nxt, 2, gBh, kt + 1); SPAIR(nxt, 3, gBl, kt + 1); }
        __builtin_amdgcn_s_setprio(1);
        MFMA_HALF(1);
        __builtin_amdgcn_s_setprio(0);
    }

    // epilogue. D col=lane&15 (N), row=(lane>>4)*4+r (M) [m89-verified].
    // M row m = s*64+b  =>  s = bm*4 + wr*2 + (ai>>2), b = (ai&3)*16 +
    // (lane>>4)*4 + r. Pair (s even, s odd) = (acc[al], acc[al+4]), al<4.
    int n0 = bn * BN;
    if (n0 < 2 * HDIM) {
        // pc (c=0) / pa (c=2) -> paired-interleaved ws layout:
        // float addr = p*4*STRIDE + idx*4 + c, p = s>>1 = bm*2+wr, idx = b*HDIM+n
        int c = (n0 < HDIM) ? 0 : 2;
        int nb = n0 & (HDIM - 1);
        size_t prow = (size_t)(bm * 2 + wr) * (4 * STRIDE);
#pragma unroll
        for (int al = 0; al < 4; ++al)
#pragma unroll
            for (int bj = 0; bj < 4; ++bj) {
                int n = nb + wc * 64 + bj * 16 + (lane & 15);
#pragma unroll
                for (int r = 0; r < 4; ++r) {
                    int b = al * 16 + (lane >> 4) * 4 + r;
                    f32x2 v = {acc[al][bj][r], acc[al + 4][bj][r]};
                    *(f32x2*)(pcpa + prow + (size_t)(b * HDIM + n) * 4 + c) = v;
                }
            }
    } else {
        // ph -> out[s][b][j] = out[m*HDIM + n] (recur overwrites in place)
        int nb = n0 - 2 * HDIM;
#pragma unroll
        for (int ai = 0; ai < 8; ++ai)
#pragma unroll
            for (int bj = 0; bj < 4; ++bj) {
                int m = bm * BM + wr * 128 + ai * 16 + (lane >> 4) * 4;
                int n = nb + wc * 64 + bj * 16 + (lane & 15);
#pragma unroll
                for (int r = 0; r < 4; ++r)
                    out[(size_t)(m + r) * HDIM + n] = acc[ai][bj][r];
            }
    }
#undef SPAIR
#undef READ_A
#undef READ_B
#undef MFMA_HALF
}

// ------------------------- recurrence ------------------------------------
// one thread per (b,j); 65536 threads. pc/pa arrive as one float4 per
// 2 steps from the paired layout; ph in-place in out. 32-step pipeline:
// 16 float4 + 32 dword = 48 outstanding loads (<=63 vmcnt slots), in-flight
// bytes 24.6 KB/SIMD >= 22.5 KB BW*latency product -> HBM saturation.
// libm transcendentals (r8: fast variants null — BW-bound).
__global__ __launch_bounds__(256) void recur(const float* __restrict__ pcpa,
                                             float* out,
                                             const float* __restrict__ h0,
                                             const float* __restrict__ wc_,
                                             const float* __restrict__ bc_,
                                             const float* __restrict__ wa_,
                                             const float* __restrict__ ba_,
                                             const float* __restrict__ bh_) {
    int idx = blockIdx.x * 256 + threadIdx.x;
    int j = idx & (HDIM - 1);
    float h  = h0[idx];
    float wc = wc_[j], bc = bc_[j];
    float wa = wa_[j], ba = ba_[j];
    float bh = bh_[j];

    const f32x4* PP = (const f32x4*)pcpa;   // element (p, idx) = PP[p*STRIDE+idx]

#define NP 16   // pairs per pipeline stage = 32 steps
    f32x4 pp[NP];
    float ph[2 * NP];
#pragma unroll
    for (int u = 0; u < NP; ++u) {
        pp[u] = PP[(size_t)u * STRIDE + idx];
        ph[2 * u]     = out[(size_t)(2 * u) * STRIDE + idx];
        ph[2 * u + 1] = out[(size_t)(2 * u + 1) * STRIDE + idx];
    }

    for (int sb = 0; sb < SEQLEN; sb += 2 * NP) {
#pragma unroll
        for (int u = 0; u < NP; ++u) {
            int s = sb + 2 * u;
            float vc0 = pp[u][0], vc1 = pp[u][1];
            float va0 = pp[u][2], va1 = pp[u][3];
            float vh0 = ph[2 * u], vh1 = ph[2 * u + 1];

            // prefetch next stage (clamped dead-prefetch at the tail)
            int pn = (sb >> 1) + u + NP; pn = (pn < SEQLEN / 2) ? pn : (SEQLEN / 2 - 1);
            pp[u] = PP[(size_t)pn * STRIDE + idx];
            int sp0 = s + 2 * NP;     sp0 = (sp0 < SEQLEN) ? sp0 : (SEQLEN - 1);
            int sp1 = s + 2 * NP + 1; sp1 = (sp1 < SEQLEN) ? sp1 : (SEQLEN - 1);
            ph[2 * u]     = out[(size_t)sp0 * STRIDE + idx];
            ph[2 * u + 1] = out[(size_t)sp1 * STRIDE + idx];

            // step s (even)
            float zc = (vc0 + bc) + wc * h;
            float za = (va0 + ba) + wa * h;
            float c  = 1.0f / (1.0f + expf(-zc));
            float a  = 1.0f + tanhf(za);
            float ht = tanhf((vh0 + bh) + a * h);
            h = c * h + (1.0f - c) * ht;
            out[(size_t)s * STRIDE + idx] = h;
            // step s+1 (odd)
            zc = (vc1 + bc) + wc * h;
            za = (va1 + ba) + wa * h;
            c  = 1.0f / (1.0f + expf(-zc));
            a  = 1.0f + tanhf(za);
            ht = tanhf((vh1 + bh) + a * h);
            h = c * h + (1.0f - c) * ht;
            out[(size_t)(s + 1) * STRIDE + idx] = h;
        }
    }
    out[(size_t)SEQLEN * STRIDE + idx] = h;   // hn
#undef NP
}

// --------------------------- launch --------------------------------------
extern "C" void kernel_launch(void* const* d_in, const int* in_sizes, int n_in,
                              void* d_out, int out_size, void* d_ws, size_t ws_size,
                              hipStream_t stream) {
    const float* x_seq = (const float*)d_in[0];
    const float* h0    = (const float*)d_in[1];
    const float* U_c   = (const float*)d_in[2];
    const float* w_c   = (const float*)d_in[3];
    const float* b_c   = (const float*)d_in[4];
    const float* U_a   = (const float*)d_in[5];
    const float* w_a   = (const float*)d_in[6];
    const float* b_a   = (const float*)d_in[7];
    const float* U_h   = (const float*)d_in[8];
    const float* b_h   = (const float*)d_in[9];
    float* out = (float*)d_out;

    char* ws = (char*)d_ws;
    const size_t MB = 1024 * 1024;
    float*    ws_pcpa = (float*)ws;                      // 256 MB paired pc/pa
    _Float16* x_hi  = (_Float16*)(ws + 256 * MB);        // 32 MB
    _Float16* x_lo  = (_Float16*)(ws + 288 * MB);        // 32 MB
    _Float16* u_hi  = (_Float16*)(ws + 320 * MB);        // 3 MB
    _Float16* u_lo  = (_Float16*)(ws + 323 * MB);        // 3 MB

    cvt_all<<<dim3((XTHREADS + UTHREADS) / 256), dim3(256), 0, stream>>>(
        x_seq, U_c, U_a, U_h, x_hi, x_lo, u_hi, u_lo);
    gemm_f16x2<<<dim3(GRID), dim3(512), 0, stream>>>(
        x_hi, x_lo, u_hi, u_lo, ws_pcpa, out);
    recur<<<dim3(STRIDE / 256), dim3(256), 0, stream>>>(ws_pcpa, out, h0,
                                                        w_c, b_c, w_a, b_a, b_h);
}